// Round 1
// baseline (423.587 us; speedup 1.0000x reference)
//
#include <hip/hip_runtime.h>
#include <hip/hip_bf16.h>
#include <math.h>

typedef __bf16 bf16_t;
typedef __bf16 bf16x8 __attribute__((ext_vector_type(8)));
typedef float f32x4 __attribute__((ext_vector_type(4)));

#define MFMA_B16(a, b, c) __builtin_amdgcn_mfma_f32_16x16x32_bf16((a), (b), (c), 0, 0, 0)

static constexpr int Bn = 2, Sn = 2048, Dn = 768, Hn = 12, DKn = 64, Fn = 3072;
static constexpr int NTOK = Bn * Sn;  // 4096

// ---------------- transpose + f32->bf16 : dst[q][p] = src[p][q] ----------------
// src is P x Q f32 (row-major), dst is Q x P bf16 (row-major). Batched via grid.y.
__global__ __launch_bounds__(256) void k_transpose_cvt(const float* __restrict__ src,
                                                       bf16_t* __restrict__ dst,
                                                       int P, int Q, long sstride, long dstride) {
  __shared__ float T[64][65];
  int nQ = Q >> 6;
  int tp = blockIdx.x / nQ;
  int tq = blockIdx.x - tp * nQ;
  src += (long)blockIdx.y * sstride;
  dst += (long)blockIdx.y * dstride;
  int j = threadIdx.x & 63, i0 = threadIdx.x >> 6;
#pragma unroll
  for (int i = i0; i < 64; i += 4)
    T[i][j] = src[(size_t)(tp * 64 + i) * Q + tq * 64 + j];
  __syncthreads();
#pragma unroll
  for (int i = i0; i < 64; i += 4)
    dst[(size_t)(tq * 64 + i) * P + tp * 64 + j] = (bf16_t)T[j][i];
}

__global__ __launch_bounds__(256) void k_concat3(const float* __restrict__ a,
                                                 const float* __restrict__ b,
                                                 const float* __restrict__ c,
                                                 float* __restrict__ dst) {
  int i = blockIdx.x * 256 + threadIdx.x;
  if (i < 768) dst[i] = a[i];
  else if (i < 1536) dst[i] = b[i - 768];
  else if (i < 2304) dst[i] = c[i - 1536];
}

// ---------------- LayerNorm over D=768, one token per block ----------------
__global__ __launch_bounds__(256) void k_layernorm(const float* __restrict__ x,
                                                   const float* __restrict__ g,
                                                   const float* __restrict__ bb,
                                                   bf16_t* __restrict__ out) {
  int t = blockIdx.x, tid = threadIdx.x;
  const float* xr = x + (size_t)t * Dn;
  float v0 = xr[tid], v1 = xr[tid + 256], v2 = xr[tid + 512];
  float s = v0 + v1 + v2;
  float ss = v0 * v0 + v1 * v1 + v2 * v2;
  __shared__ float red[8];
#pragma unroll
  for (int off = 32; off > 0; off >>= 1) {
    s += __shfl_down(s, off);
    ss += __shfl_down(ss, off);
  }
  int w = tid >> 6, l = tid & 63;
  if (l == 0) { red[w] = s; red[4 + w] = ss; }
  __syncthreads();
  s = red[0] + red[1] + red[2] + red[3];
  ss = red[4] + red[5] + red[6] + red[7];
  float mu = s * (1.0f / Dn);
  float var = ss * (1.0f / Dn) - mu * mu;
  float rstd = rsqrtf(var + 1e-5f);
  bf16_t* orow = out + (size_t)t * Dn;
  orow[tid]       = (bf16_t)((v0 - mu) * rstd * g[tid]       + bb[tid]);
  orow[tid + 256] = (bf16_t)((v1 - mu) * rstd * g[tid + 256] + bb[tid + 256]);
  orow[tid + 512] = (bf16_t)((v2 - mu) * rstd * g[tid + 512] + bb[tid + 512]);
}

// ---------------- bf16 MFMA GEMM: C = A(MxK) * Bt(NxK)^T, fused epilogues ----------------
enum { EPI_QKV = 0, EPI_Y = 1, EPI_GELU = 2, EPI_OUT = 3 };

template <int EPI>
__global__ __launch_bounds__(256, 2) void k_gemm(const bf16_t* __restrict__ A,
                                                 const bf16_t* __restrict__ Bt,
                                                 int M, int N, int K,
                                                 const float* __restrict__ bias,
                                                 const float* __restrict__ resid,
                                                 void* __restrict__ out0,
                                                 void* __restrict__ out1,
                                                 void* __restrict__ out2) {
  (void)M;
  __shared__ __align__(16) bf16_t As[128 * 32];
  __shared__ __align__(16) bf16_t Bs[128 * 32];
  const int tid = threadIdx.x;
  const int w = tid >> 6, l = tid & 63;
  const int wm = w >> 1, wn = w & 1;
  const int mloc = l & 15, kblk = l >> 4;
  const int bx = blockIdx.x, by = blockIdx.y;

  f32x4 acc[4][4];
#pragma unroll
  for (int i = 0; i < 4; ++i)
#pragma unroll
    for (int j = 0; j < 4; ++j) acc[i][j] = f32x4{0.f, 0.f, 0.f, 0.f};

  // staging: 512 chunks of 16B per tile; thread handles chunks tid (rows 0..63) and tid+256 (rows 64..127)
  const int r0 = tid >> 2, ko0 = (tid & 3) * 8;
  const bf16_t* gA0 = A + (size_t)(by * 128 + r0) * K + ko0;
  const bf16_t* gA1 = A + (size_t)(by * 128 + r0 + 64) * K + ko0;
  const bf16_t* gB0 = Bt + (size_t)(bx * 128 + r0) * K + ko0;
  const bf16_t* gB1 = Bt + (size_t)(bx * 128 + r0 + 64) * K + ko0;
  bf16_t* lA0 = &As[r0 * 32 + ko0];
  bf16_t* lA1 = &As[(r0 + 64) * 32 + ko0];
  bf16_t* lB0 = &Bs[r0 * 32 + ko0];
  bf16_t* lB1 = &Bs[(r0 + 64) * 32 + ko0];

  const int nk = K >> 5;
  for (int kt = 0; kt < nk; ++kt) {
    uint4 a0 = *(const uint4*)gA0;
    uint4 a1 = *(const uint4*)gA1;
    uint4 b0 = *(const uint4*)gB0;
    uint4 b1 = *(const uint4*)gB1;
    gA0 += 32; gA1 += 32; gB0 += 32; gB1 += 32;
    __syncthreads();               // prior iteration's LDS reads finished
    *(uint4*)lA0 = a0;
    *(uint4*)lA1 = a1;
    *(uint4*)lB0 = b0;
    *(uint4*)lB1 = b1;
    __syncthreads();               // staging visible
    bf16x8 af[4], bfv[4];
#pragma unroll
    for (int mi = 0; mi < 4; ++mi)
      af[mi] = *(const bf16x8*)&As[(wm * 64 + mi * 16 + mloc) * 32 + kblk * 8];
#pragma unroll
    for (int ni = 0; ni < 4; ++ni)
      bfv[ni] = *(const bf16x8*)&Bs[(wn * 64 + ni * 16 + mloc) * 32 + kblk * 8];
#pragma unroll
    for (int mi = 0; mi < 4; ++mi)
#pragma unroll
      for (int ni = 0; ni < 4; ++ni)
        acc[mi][ni] = MFMA_B16(af[mi], bfv[ni], acc[mi][ni]);
  }

  // epilogue: C/D layout row = kblk*4 + r, col = mloc  (verified m89/m91)
  const int gmb = by * 128 + wm * 64 + kblk * 4;
  const int gnb = bx * 128 + wn * 64 + mloc;
  if constexpr (EPI == EPI_QKV) {
    const int proj = bx / 6;  // 768/128 tiles per projection; uniform per block
    bf16_t* dst = proj == 0 ? (bf16_t*)out0 : (proj == 1 ? (bf16_t*)out1 : (bf16_t*)out2);
    const int nsub = proj * 768;
#pragma unroll
    for (int mi = 0; mi < 4; ++mi)
#pragma unroll
      for (int ni = 0; ni < 4; ++ni) {
        int gn = gnb + ni * 16;
        float bv = bias[gn];
#pragma unroll
        for (int r = 0; r < 4; ++r) {
          int gm = gmb + mi * 16 + r;
          dst[(size_t)gm * 768 + (gn - nsub)] = (bf16_t)(acc[mi][ni][r] + bv);
        }
      }
  } else if constexpr (EPI == EPI_GELU) {
    bf16_t* dst = (bf16_t*)out0;
#pragma unroll
    for (int mi = 0; mi < 4; ++mi)
#pragma unroll
      for (int ni = 0; ni < 4; ++ni) {
        int gn = gnb + ni * 16;
        float bv = bias[gn];
#pragma unroll
        for (int r = 0; r < 4; ++r) {
          int gm = gmb + mi * 16 + r;
          float t = acc[mi][ni][r] + bv;
          float ge = 0.5f * t * (1.0f + erff(t * 0.70710678118654752f));
          dst[(size_t)gm * N + gn] = (bf16_t)ge;
        }
      }
  } else {  // EPI_Y / EPI_OUT: + bias + residual, fp32 out
    float* dst = (float*)out0;
#pragma unroll
    for (int mi = 0; mi < 4; ++mi)
#pragma unroll
      for (int ni = 0; ni < 4; ++ni) {
        int gn = gnb + ni * 16;
        float bv = bias[gn];
#pragma unroll
        for (int r = 0; r < 4; ++r) {
          int gm = gmb + mi * 16 + r;
          dst[(size_t)gm * N + gn] = acc[mi][ni][r] + bv + resid[(size_t)gm * N + gn];
        }
      }
  }
}

// ---------------- flash attention: 64 q-rows/block, KV tiles of 64, online softmax ----------------
__global__ __launch_bounds__(256, 2) void k_attn(const bf16_t* __restrict__ Q,
                                                 const bf16_t* __restrict__ K,
                                                 const bf16_t* __restrict__ V,
                                                 bf16_t* __restrict__ O) {
  __shared__ __align__(16) bf16_t Ks[64 * 72];      // [kv][dk], padded
  __shared__ __align__(16) bf16_t Vs[64 * 72];      // [dk][kv], padded (transposed)
  __shared__ __align__(16) bf16_t Ps[4][16 * 72];   // per-wave P tile [m][kv]
  const int tid = threadIdx.x, w = tid >> 6, l = tid & 63;
  const int mloc = l & 15, kblk = l >> 4;
  const int bh = blockIdx.y, b = bh / Hn, h = bh - b * Hn;
  const int q0 = blockIdx.x * 64;

  // Q fragments (A-layout: m = mloc, k = kblk*8 + j), DK=64 -> two frags
  const size_t qoff = ((size_t)(b * Sn + q0 + w * 16 + mloc)) * Dn + h * 64 + kblk * 8;
  bf16x8 qf0 = *(const bf16x8*)(Q + qoff);
  bf16x8 qf1 = *(const bf16x8*)(Q + qoff + 32);

  float m_i[4], l_i[4];
  f32x4 oacc[4];
#pragma unroll
  for (int r = 0; r < 4; ++r) { m_i[r] = -INFINITY; l_i[r] = 0.f; }
#pragma unroll
  for (int nd = 0; nd < 4; ++nd) oacc[nd] = f32x4{0.f, 0.f, 0.f, 0.f};

  const int sr0 = tid >> 3, sc0 = tid & 7;  // staging: rows sr0, sr0+32; 16B chunk sc0
  const size_t kvbase = ((size_t)b * Sn) * Dn + h * 64;

  for (int it = 0; it < Sn / 64; ++it) {
    const int kv0 = it * 64;
    const bf16_t* kp0 = K + kvbase + (size_t)(kv0 + sr0) * Dn + sc0 * 8;
    const bf16_t* kp1 = kp0 + (size_t)32 * Dn;
    const bf16_t* vp0 = V + kvbase + (size_t)(kv0 + sr0) * Dn + sc0 * 8;
    const bf16_t* vp1 = vp0 + (size_t)32 * Dn;
    uint4 ka = *(const uint4*)kp0;
    uint4 kc = *(const uint4*)kp1;
    bf16x8 va = *(const bf16x8*)vp0;
    bf16x8 vb = *(const bf16x8*)vp1;
    __syncthreads();
    *(uint4*)&Ks[sr0 * 72 + sc0 * 8] = ka;
    *(uint4*)&Ks[(sr0 + 32) * 72 + sc0 * 8] = kc;
#pragma unroll
    for (int j = 0; j < 8; ++j) {
      Vs[(sc0 * 8 + j) * 72 + sr0] = va[j];
      Vs[(sc0 * 8 + j) * 72 + sr0 + 32] = vb[j];
    }
    __syncthreads();

    // scores: 16(m) x 64(kv) per wave
    float sc[4][4];
#pragma unroll
    for (int ns = 0; ns < 4; ++ns) {
      const bf16_t* kr = &Ks[(ns * 16 + mloc) * 72 + kblk * 8];
      f32x4 a = f32x4{0.f, 0.f, 0.f, 0.f};
      a = MFMA_B16(qf0, *(const bf16x8*)kr, a);
      a = MFMA_B16(qf1, *(const bf16x8*)(kr + 32), a);
#pragma unroll
      for (int r = 0; r < 4; ++r) sc[ns][r] = a[r] * 0.125f;  // 1/sqrt(64)
    }

    // online softmax per row (row = kblk*4 + r; 16 cols per ns spread over quad lanes)
#pragma unroll
    for (int r = 0; r < 4; ++r) {
      float mx = fmaxf(fmaxf(sc[0][r], sc[1][r]), fmaxf(sc[2][r], sc[3][r]));
#pragma unroll
      for (int off = 1; off < 16; off <<= 1) mx = fmaxf(mx, __shfl_xor(mx, off));
      float mnew = fmaxf(m_i[r], mx);
      float al = __expf(m_i[r] - mnew);
      float rs = 0.f;
#pragma unroll
      for (int ns = 0; ns < 4; ++ns) {
        float p = __expf(sc[ns][r] - mnew);
        sc[ns][r] = p;
        rs += p;
      }
#pragma unroll
      for (int off = 1; off < 16; off <<= 1) rs += __shfl_xor(rs, off);
      m_i[r] = mnew;
      l_i[r] = l_i[r] * al + rs;
#pragma unroll
      for (int nd = 0; nd < 4; ++nd) oacc[nd][r] *= al;
    }

    // P (C-layout) -> LDS -> A-layout for PV
    bf16_t* pw = Ps[w];
#pragma unroll
    for (int ns = 0; ns < 4; ++ns)
#pragma unroll
      for (int r = 0; r < 4; ++r)
        pw[(kblk * 4 + r) * 72 + ns * 16 + mloc] = (bf16_t)sc[ns][r];

    const bf16_t* pr = &Ps[w][mloc * 72 + kblk * 8];
    bf16x8 p0 = *(const bf16x8*)pr;
    bf16x8 p1 = *(const bf16x8*)(pr + 32);
#pragma unroll
    for (int nd = 0; nd < 4; ++nd) {
      const bf16_t* vr = &Vs[(nd * 16 + mloc) * 72 + kblk * 8];
      oacc[nd] = MFMA_B16(p0, *(const bf16x8*)vr, oacc[nd]);
      oacc[nd] = MFMA_B16(p1, *(const bf16x8*)(vr + 32), oacc[nd]);
    }
  }

  // normalize + write (C-layout: row = kblk*4 + r, col = nd*16 + mloc)
  const size_t obase = ((size_t)(b * Sn + q0 + w * 16 + kblk * 4)) * Dn + h * 64 + mloc;
#pragma unroll
  for (int r = 0; r < 4; ++r) {
    float inv = 1.0f / l_i[r];
#pragma unroll
    for (int nd = 0; nd < 4; ++nd)
      O[obase + (size_t)r * Dn + nd * 16] = (bf16_t)(oacc[nd][r] * inv);
  }
}

// ---------------- host launch ----------------
extern "C" void kernel_launch(void* const* d_in, const int* in_sizes, int n_in,
                              void* d_out, int out_size, void* d_ws, size_t ws_size,
                              hipStream_t stream) {
  (void)in_sizes; (void)n_in; (void)out_size; (void)ws_size;
  const float* x    = (const float*)d_in[0];
  const float* wq_w = (const float*)d_in[1];
  const float* wq_b = (const float*)d_in[2];
  const float* wk_w = (const float*)d_in[3];
  const float* wk_b = (const float*)d_in[4];
  const float* wv_w = (const float*)d_in[5];
  const float* wv_b = (const float*)d_in[6];
  const float* wo_w = (const float*)d_in[7];
  const float* wo_b = (const float*)d_in[8];
  const float* ln_g = (const float*)d_in[9];
  const float* ln_b = (const float*)d_in[10];
  const float* w1   = (const float*)d_in[11];
  const float* b1   = (const float*)d_in[12];
  const float* w2   = (const float*)d_in[13];
  const float* b2   = (const float*)d_in[14];

  char* ws = (char*)d_ws;
  size_t o = 0;
  bf16_t* WqkvT = (bf16_t*)(ws + o); o += (size_t)2304 * 768 * 2;
  bf16_t* WoT   = (bf16_t*)(ws + o); o += (size_t)768 * 768 * 2;
  bf16_t* W1T   = (bf16_t*)(ws + o); o += (size_t)3072 * 768 * 2;
  bf16_t* W2T   = (bf16_t*)(ws + o); o += (size_t)768 * 3072 * 2;
  float*  QKVB  = (float*)(ws + o);  o += (size_t)2304 * 4;
  bf16_t* Hbuf  = (bf16_t*)(ws + o); o += (size_t)NTOK * 768 * 2;  // h, later reused as o
  bf16_t* Qb    = (bf16_t*)(ws + o); o += (size_t)NTOK * 768 * 2;
  bf16_t* Kb    = (bf16_t*)(ws + o); o += (size_t)NTOK * 768 * 2;
  bf16_t* Vb    = (bf16_t*)(ws + o); o += (size_t)NTOK * 768 * 2;
  float*  Ybuf  = (float*)(ws + o);  o += (size_t)NTOK * 768 * 4;
  bf16_t* Zbuf  = (bf16_t*)(ws + o); o += (size_t)NTOK * 768 * 2;
  bf16_t* Ubuf  = (bf16_t*)(ws + o); o += (size_t)NTOK * 3072 * 2;

  // --- weight prep (bf16 + transpose to NxK) ---
  // QKV: per proj, per head h: src (768 d x 64 dk) -> dst (64 dk x 768 d)
  k_transpose_cvt<<<dim3(12, 12), 256, 0, stream>>>(wq_w, WqkvT,               768, 64, 768 * 64, 64 * 768);
  k_transpose_cvt<<<dim3(12, 12), 256, 0, stream>>>(wk_w, WqkvT + 589824,      768, 64, 768 * 64, 64 * 768);
  k_transpose_cvt<<<dim3(12, 12), 256, 0, stream>>>(wv_w, WqkvT + 2 * 589824,  768, 64, 768 * 64, 64 * 768);
  // Wo: (768 hk x 768 dout) -> (dout x hk)
  k_transpose_cvt<<<dim3(144, 1), 256, 0, stream>>>(wo_w, WoT, 768, 768, 0, 0);
  // W1: (768 d x 3072 f) -> (f x d);  W2: (3072 f x 768 d) -> (d x f)
  k_transpose_cvt<<<dim3(12 * 48, 1), 256, 0, stream>>>(w1, W1T, 768, 3072, 0, 0);
  k_transpose_cvt<<<dim3(48 * 12, 1), 256, 0, stream>>>(w2, W2T, 3072, 768, 0, 0);
  k_concat3<<<9, 256, 0, stream>>>(wq_b, wk_b, wv_b, QKVB);

  // --- LN1 -> h (bf16) ---
  k_layernorm<<<NTOK, 256, 0, stream>>>(x, ln_g, ln_b, Hbuf);

  // --- QKV projection: [4096 x 768] @ [2304 x 768]^T -> Q,K,V bf16 ---
  k_gemm<EPI_QKV><<<dim3(18, 32), 256, 0, stream>>>(Hbuf, WqkvT, NTOK, 2304, 768,
                                                    QKVB, nullptr, Qb, Kb, Vb);

  // --- attention -> o (bf16, reuses Hbuf) ---
  k_attn<<<dim3(Sn / 64, Bn * Hn), 256, 0, stream>>>(Qb, Kb, Vb, Hbuf);

  // --- y = o @ Wo + wo_b + x (fp32) ---
  k_gemm<EPI_Y><<<dim3(6, 32), 256, 0, stream>>>(Hbuf, WoT, NTOK, 768, 768,
                                                 wo_b, x, Ybuf, nullptr, nullptr);

  // --- LN2 -> z (bf16) ---
  k_layernorm<<<NTOK, 256, 0, stream>>>(Ybuf, ln_g, ln_b, Zbuf);

  // --- FFN1 + exact GELU -> u (bf16) ---
  k_gemm<EPI_GELU><<<dim3(24, 32), 256, 0, stream>>>(Zbuf, W1T, NTOK, 3072, 768,
                                                     b1, nullptr, Ubuf, nullptr, nullptr);

  // --- FFN2 + b2 + y -> out (fp32) ---
  k_gemm<EPI_OUT><<<dim3(6, 32), 256, 0, stream>>>(Ubuf, W2T, NTOK, 768, 3072,
                                                   b2, Ybuf, d_out, nullptr, nullptr);
}

// Round 2
// 336.984 us; speedup vs baseline: 1.2570x; 1.2570x over previous
//
#include <hip/hip_runtime.h>
#include <hip/hip_bf16.h>
#include <math.h>

typedef __bf16 bf16_t;
typedef __bf16 bf16x8 __attribute__((ext_vector_type(8)));
typedef __bf16 bf16x4 __attribute__((ext_vector_type(4)));
typedef float f32x4 __attribute__((ext_vector_type(4)));

#define MFMA_B16(a, b, c) __builtin_amdgcn_mfma_f32_16x16x32_bf16((a), (b), (c), 0, 0, 0)

static constexpr int Bn = 2, Sn = 2048, Dn = 768, Hn = 12, Fn = 3072;
static constexpr int NTOK = Bn * Sn;  // 4096
// 0.125 (1/sqrt(dk)) * log2(e): folded into Q so softmax uses exp2
#define QSCALE 0.18033688011112042f

// async global->LDS, 16B per lane; lds must be wave-uniform base (HW adds lane*16)
__device__ __forceinline__ void gl_lds16(const bf16_t* g, void* lds) {
  __builtin_amdgcn_global_load_lds(
      (const __attribute__((address_space(1))) uint32_t*)g,
      (__attribute__((address_space(3))) uint32_t*)lds, 16, 0, 0);
}

// ---------------- weight transpose + f32->bf16 : dst[q][p] = src[p][q] ----------------
__global__ __launch_bounds__(256) void k_transpose_cvt(const float* __restrict__ src,
                                                       bf16_t* __restrict__ dst,
                                                       int P, int Q) {
  __shared__ float T[64][65];
  int nQ = Q >> 6;
  int tp = blockIdx.x / nQ;
  int tq = blockIdx.x - tp * nQ;
  int j = threadIdx.x & 63, i0 = threadIdx.x >> 6;
#pragma unroll
  for (int i = i0; i < 64; i += 4)
    T[i][j] = src[(size_t)(tp * 64 + i) * Q + tq * 64 + j];
  __syncthreads();
#pragma unroll
  for (int i = i0; i < 64; i += 4)
    dst[(size_t)(tq * 64 + i) * P + tp * 64 + j] = (bf16_t)T[j][i];
}

// merged QKV weight transpose: grid (12, 36); by = proj*12 + head
__global__ __launch_bounds__(256) void k_transpose_qkv(const float* __restrict__ wq,
                                                       const float* __restrict__ wk,
                                                       const float* __restrict__ wv,
                                                       bf16_t* __restrict__ dst) {
  __shared__ float T[64][65];
  int pb = blockIdx.y, proj = pb / 12, head = pb - proj * 12;
  const float* src = (proj == 0 ? wq : (proj == 1 ? wk : wv)) + (size_t)head * 768 * 64;
  bf16_t* d = dst + (size_t)proj * 589824 + (size_t)head * 64 * 768;
  int tp = blockIdx.x;
  int j = threadIdx.x & 63, i0 = threadIdx.x >> 6;
#pragma unroll
  for (int i = i0; i < 64; i += 4)
    T[i][j] = src[(size_t)(tp * 64 + i) * 64 + j];
  __syncthreads();
#pragma unroll
  for (int i = i0; i < 64; i += 4)
    d[(size_t)i * 768 + tp * 64 + j] = (bf16_t)T[j][i];
}

__global__ __launch_bounds__(256) void k_concat3(const float* __restrict__ a,
                                                 const float* __restrict__ b,
                                                 const float* __restrict__ c,
                                                 float* __restrict__ dst) {
  int i = blockIdx.x * 256 + threadIdx.x;
  if (i < 768) dst[i] = a[i];
  else if (i < 1536) dst[i] = b[i - 768];
  else if (i < 2304) dst[i] = c[i - 1536];
}

// ---------------- LayerNorm over D=768, one token per block ----------------
__global__ __launch_bounds__(256) void k_layernorm(const float* __restrict__ x,
                                                   const float* __restrict__ g,
                                                   const float* __restrict__ bb,
                                                   bf16_t* __restrict__ out) {
  int t = blockIdx.x, tid = threadIdx.x;
  const float* xr = x + (size_t)t * Dn;
  float v0 = xr[tid], v1 = xr[tid + 256], v2 = xr[tid + 512];
  float s = v0 + v1 + v2;
  float ss = v0 * v0 + v1 * v1 + v2 * v2;
  __shared__ float red[8];
#pragma unroll
  for (int off = 32; off > 0; off >>= 1) {
    s += __shfl_down(s, off);
    ss += __shfl_down(ss, off);
  }
  int w = tid >> 6, l = tid & 63;
  if (l == 0) { red[w] = s; red[4 + w] = ss; }
  __syncthreads();
  s = red[0] + red[1] + red[2] + red[3];
  ss = red[4] + red[5] + red[6] + red[7];
  float mu = s * (1.0f / Dn);
  float var = ss * (1.0f / Dn) - mu * mu;
  float rstd = rsqrtf(var + 1e-5f);
  bf16_t* orow = out + (size_t)t * Dn;
  orow[tid]       = (bf16_t)((v0 - mu) * rstd * g[tid]       + bb[tid]);
  orow[tid + 256] = (bf16_t)((v1 - mu) * rstd * g[tid + 256] + bb[tid + 256]);
  orow[tid + 512] = (bf16_t)((v2 - mu) * rstd * g[tid + 512] + bb[tid + 512]);
}

// ---------------- bf16 MFMA GEMM: C = A(MxK) * Bt(NxK)^T, global_load_lds staging ----------------
enum { EPI_QKV = 0, EPI_Y = 1, EPI_GELU = 2, EPI_OUT = 3 };

template <int MT, int EPI>
__global__ __launch_bounds__(256, 2) void k_gemm(const bf16_t* __restrict__ A,
                                                 const bf16_t* __restrict__ Bt,
                                                 int N, int K,
                                                 const float* __restrict__ bias,
                                                 const float* __restrict__ resid,
                                                 void* __restrict__ out0,
                                                 void* __restrict__ out1,
                                                 void* __restrict__ out2) {
  constexpr int MI = (MT == 128) ? 4 : 2;       // acc tiles in m per wave
  constexpr int WROWS = MT / 2;                 // rows per wave-m-half
  __shared__ __align__(16) bf16_t As[MT * 32];
  __shared__ __align__(16) bf16_t Bs[128 * 32];
  const int tid = threadIdx.x;
  const int w = tid >> 6, l = tid & 63;
  const int wm = w >> 1, wn = w & 1;
  const int mloc = l & 15, kblk = l >> 4;
  const int bx = blockIdx.x, by = blockIdx.y;

  f32x4 acc[MI][4];
#pragma unroll
  for (int i = 0; i < MI; ++i)
#pragma unroll
    for (int j = 0; j < 4; ++j) acc[i][j] = f32x4{0.f, 0.f, 0.f, 0.f};

  const int r0 = tid >> 2, ko0 = (tid & 3) * 8;
  const bf16_t* gA = A + (size_t)(by * MT + r0) * K + ko0;
  const bf16_t* gB = Bt + (size_t)(bx * 128 + r0) * K + ko0;
  char* lA = (char*)As + w * 1024;
  char* lB = (char*)Bs + w * 1024;

  const int nk = K >> 5;
  for (int kt = 0; kt < nk; ++kt) {
    __syncthreads();               // prior iteration's LDS reads finished
    gl_lds16(gA, lA);
    if constexpr (MT == 128) gl_lds16(gA + (size_t)64 * K, (char*)lA + 4096);
    gl_lds16(gB, lB);
    gl_lds16(gB + (size_t)64 * K, (char*)lB + 4096);
    gA += 32; gB += 32;
    __syncthreads();               // vmcnt(0) drained before barrier -> data visible
    bf16x8 af[MI], bfv[4];
#pragma unroll
    for (int mi = 0; mi < MI; ++mi)
      af[mi] = *(const bf16x8*)&As[(wm * WROWS + mi * 16 + mloc) * 32 + kblk * 8];
#pragma unroll
    for (int ni = 0; ni < 4; ++ni)
      bfv[ni] = *(const bf16x8*)&Bs[(wn * 64 + ni * 16 + mloc) * 32 + kblk * 8];
#pragma unroll
    for (int mi = 0; mi < MI; ++mi)
#pragma unroll
      for (int ni = 0; ni < 4; ++ni)
        acc[mi][ni] = MFMA_B16(af[mi], bfv[ni], acc[mi][ni]);
  }

  // epilogue: C/D layout row = kblk*4 + r, col = mloc
  const int gmb = by * MT + wm * WROWS + kblk * 4;
  const int gnb = bx * 128 + wn * 64 + mloc;
  if constexpr (EPI == EPI_QKV) {
    const int proj = bx / 6;  // 6 n-tiles per projection
#pragma unroll
    for (int mi = 0; mi < MI; ++mi)
#pragma unroll
      for (int ni = 0; ni < 4; ++ni) {
        int gn = gnb + ni * 16;
        float bv = bias[gn];
        int gm0 = gmb + mi * 16;
        if (proj == 0) {            // Q, pre-scaled for exp2 softmax
          bf16_t* dst = (bf16_t*)out0;
#pragma unroll
          for (int r = 0; r < 4; ++r)
            dst[(size_t)(gm0 + r) * 768 + gn] = (bf16_t)((acc[mi][ni][r] + bv) * QSCALE);
        } else if (proj == 1) {     // K natural
          bf16_t* dst = (bf16_t*)out1;
#pragma unroll
          for (int r = 0; r < 4; ++r)
            dst[(size_t)(gm0 + r) * 768 + (gn - 768)] = (bf16_t)(acc[mi][ni][r] + bv);
        } else {                    // V transposed: VbT[b*12+h][dk][s]
          bf16_t* dst = (bf16_t*)out2;
          int vcol = gn - 1536, hh = vcol >> 6, dk = vcol & 63;
          int bb2 = gm0 >> 11, s0v = gm0 & 2047;
          bf16x4 pk;
#pragma unroll
          for (int r = 0; r < 4; ++r) pk[r] = (bf16_t)(acc[mi][ni][r] + bv);
          *(bf16x4*)&dst[((size_t)(bb2 * Hn + hh) * 64 + dk) * Sn + s0v] = pk;
        }
      }
  } else if constexpr (EPI == EPI_GELU) {
    bf16_t* dst = (bf16_t*)out0;
#pragma unroll
    for (int mi = 0; mi < MI; ++mi)
#pragma unroll
      for (int ni = 0; ni < 4; ++ni) {
        int gn = gnb + ni * 16;
        float bv = bias[gn];
#pragma unroll
        for (int r = 0; r < 4; ++r) {
          int gm = gmb + mi * 16 + r;
          float t = acc[mi][ni][r] + bv;
          float ge = 0.5f * t * (1.0f + erff(t * 0.70710678118654752f));
          dst[(size_t)gm * N + gn] = (bf16_t)ge;
        }
      }
  } else {  // EPI_Y / EPI_OUT: + bias + residual, fp32 out
    float* dst = (float*)out0;
#pragma unroll
    for (int mi = 0; mi < MI; ++mi)
#pragma unroll
      for (int ni = 0; ni < 4; ++ni) {
        int gn = gnb + ni * 16;
        float bv = bias[gn];
#pragma unroll
        for (int r = 0; r < 4; ++r) {
          int gm = gmb + mi * 16 + r;
          dst[(size_t)gm * N + gn] = acc[mi][ni][r] + bv + resid[(size_t)gm * N + gn];
        }
      }
  }
}

// ---------------- flash attention, S^T formulation ----------------
// S^T = K·Q^T per 64-kv tile (m=kv, n=q). K rows are σ-permuted in LDS so that the
// PV B-operand (P^T fragments) is each lane's own registers: σ chosen s.t.
// σ(ns*16 + kblk*4 + r) = kstep*32 + kblk*8 + j with ns = kstep*2+(j>>2), r = j&3.
// PV computes O^T = V^T·P^T with V^T staged natural (pre-transposed VbT) -> no LDS
// transposes, no scalar LDS stores, no P round-trip.
__global__ __launch_bounds__(256, 2) void k_attn(const bf16_t* __restrict__ Q,
                                                 const bf16_t* __restrict__ K,
                                                 const bf16_t* __restrict__ VT,
                                                 bf16_t* __restrict__ O) {
  __shared__ __align__(16) bf16_t Ks[2 * 64 * 32];  // [dk-half][kv-row(σ)][32]
  __shared__ __align__(16) bf16_t Vs[2 * 64 * 32];  // [kv-half][dk][32]
  const int tid = threadIdx.x, w = tid >> 6, l = tid & 63;
  const int mloc = l & 15, kblk = l >> 4;
  const int bh = blockIdx.y, b = bh / Hn, h = bh - b * Hn;
  const int q0 = blockIdx.x * 64;

  // Q fragments (pre-scaled by QSCALE in the QKV epilogue)
  const size_t qoff = (size_t)(b * Sn + q0 + w * 16 + mloc) * Dn + h * 64 + kblk * 8;
  const bf16x8 qf0 = *(const bf16x8*)(Q + qoff);
  const bf16x8 qf1 = *(const bf16x8*)(Q + qoff + 32);

  // staging: chunk = tid -> LDS row `row`, K global row σ(row)
  const int row = tid >> 2, q4 = tid & 3;
  const int srow = (row & 0x23) | ((row & 0x0C) << 1) | ((row & 0x10) >> 2);
  const bf16_t* Kg = K + (size_t)(b * Sn + srow) * Dn + h * 64 + q4 * 8;
  const bf16_t* Vg = VT + ((size_t)bh * 64 + row) * Sn + q4 * 8;
  char* lK0 = (char*)Ks + w * 1024;
  char* lK1 = (char*)Ks + 4096 + w * 1024;
  char* lV0 = (char*)Vs + w * 1024;
  char* lV1 = (char*)Vs + 4096 + w * 1024;

  float m_i = -INFINITY, l_i = 0.f;
  f32x4 oacc[4];
#pragma unroll
  for (int md = 0; md < 4; ++md) oacc[md] = f32x4{0.f, 0.f, 0.f, 0.f};

  for (int kv0 = 0; kv0 < Sn; kv0 += 64) {
    __syncthreads();
    gl_lds16(Kg + (size_t)kv0 * Dn, lK0);
    gl_lds16(Kg + (size_t)kv0 * Dn + 32, lK1);
    gl_lds16(Vg + kv0, lV0);
    gl_lds16(Vg + kv0 + 32, lV1);
    __syncthreads();

    // S^T tiles: 4 x (16 kv x 16 q) per wave
    f32x4 st[4];
#pragma unroll
    for (int ns = 0; ns < 4; ++ns) {
      const bf16x8 k0 = *(const bf16x8*)&Ks[(ns * 16 + mloc) * 32 + kblk * 8];
      const bf16x8 k1 = *(const bf16x8*)&Ks[2048 + (ns * 16 + mloc) * 32 + kblk * 8];
      f32x4 a = f32x4{0.f, 0.f, 0.f, 0.f};
      a = MFMA_B16(k0, qf0, a);
      a = MFMA_B16(k1, qf1, a);
      st[ns] = a;
    }

    // online softmax; lane's q = mloc, state replicated across kblk quads
    float mx = -INFINITY;
#pragma unroll
    for (int ns = 0; ns < 4; ++ns)
#pragma unroll
      for (int r = 0; r < 4; ++r) mx = fmaxf(mx, st[ns][r]);
    mx = fmaxf(mx, __shfl_xor(mx, 16));
    mx = fmaxf(mx, __shfl_xor(mx, 32));
    float mnew = fmaxf(m_i, mx);
    float alpha = exp2f(m_i - mnew);
    float rs = 0.f;
#pragma unroll
    for (int ns = 0; ns < 4; ++ns)
#pragma unroll
      for (int r = 0; r < 4; ++r) {
        float p = exp2f(st[ns][r] - mnew);
        st[ns][r] = p;
        rs += p;
      }
    rs += __shfl_xor(rs, 16);
    rs += __shfl_xor(rs, 32);
    l_i = l_i * alpha + rs;
    m_i = mnew;
#pragma unroll
    for (int md = 0; md < 4; ++md)
#pragma unroll
      for (int r = 0; r < 4; ++r) oacc[md][r] *= alpha;

    // P^T B-fragments from own registers (σ alignment)
    bf16x8 pb0, pb1;
#pragma unroll
    for (int j = 0; j < 4; ++j) {
      pb0[j]     = (bf16_t)st[0][j];
      pb0[4 + j] = (bf16_t)st[1][j];
      pb1[j]     = (bf16_t)st[2][j];
      pb1[4 + j] = (bf16_t)st[3][j];
    }

    // O^T += V^T · P^T
#pragma unroll
    for (int md = 0; md < 4; ++md) {
      const bf16x8 v0 = *(const bf16x8*)&Vs[(md * 16 + mloc) * 32 + kblk * 8];
      const bf16x8 v1 = *(const bf16x8*)&Vs[2048 + (md * 16 + mloc) * 32 + kblk * 8];
      oacc[md] = MFMA_B16(v0, pb0, oacc[md]);
      oacc[md] = MFMA_B16(v1, pb1, oacc[md]);
    }
  }

  // O^T C-layout: dk = md*16 + kblk*4 + r, q = mloc -> write O[tok][768] natural
  const float inv = 1.0f / l_i;
  const size_t obase = (size_t)(b * Sn + q0 + w * 16 + mloc) * Dn + h * 64 + kblk * 4;
#pragma unroll
  for (int md = 0; md < 4; ++md) {
    bf16x4 o4;
#pragma unroll
    for (int r = 0; r < 4; ++r) o4[r] = (bf16_t)(oacc[md][r] * inv);
    *(bf16x4*)&O[obase + md * 16] = o4;
  }
}

// ---------------- host launch ----------------
extern "C" void kernel_launch(void* const* d_in, const int* in_sizes, int n_in,
                              void* d_out, int out_size, void* d_ws, size_t ws_size,
                              hipStream_t stream) {
  (void)in_sizes; (void)n_in; (void)out_size; (void)ws_size;
  const float* x    = (const float*)d_in[0];
  const float* wq_w = (const float*)d_in[1];
  const float* wq_b = (const float*)d_in[2];
  const float* wk_w = (const float*)d_in[3];
  const float* wk_b = (const float*)d_in[4];
  const float* wv_w = (const float*)d_in[5];
  const float* wv_b = (const float*)d_in[6];
  const float* wo_w = (const float*)d_in[7];
  const float* wo_b = (const float*)d_in[8];
  const float* ln_g = (const float*)d_in[9];
  const float* ln_b = (const float*)d_in[10];
  const float* w1   = (const float*)d_in[11];
  const float* b1   = (const float*)d_in[12];
  const float* w2   = (const float*)d_in[13];
  const float* b2   = (const float*)d_in[14];

  char* ws = (char*)d_ws;
  size_t o = 0;
  bf16_t* WqkvT = (bf16_t*)(ws + o); o += (size_t)2304 * 768 * 2;
  bf16_t* WoT   = (bf16_t*)(ws + o); o += (size_t)768 * 768 * 2;
  bf16_t* W1T   = (bf16_t*)(ws + o); o += (size_t)3072 * 768 * 2;
  bf16_t* W2T   = (bf16_t*)(ws + o); o += (size_t)768 * 3072 * 2;
  float*  QKVB  = (float*)(ws + o);  o += (size_t)2304 * 4;
  bf16_t* Hbuf  = (bf16_t*)(ws + o); o += (size_t)NTOK * 768 * 2;  // h, later reused as o
  bf16_t* Qb    = (bf16_t*)(ws + o); o += (size_t)NTOK * 768 * 2;
  bf16_t* Kb    = (bf16_t*)(ws + o); o += (size_t)NTOK * 768 * 2;
  bf16_t* VbT   = (bf16_t*)(ws + o); o += (size_t)NTOK * 768 * 2;  // [b*12+h][64][2048]
  float*  Ybuf  = (float*)(ws + o);  o += (size_t)NTOK * 768 * 4;
  bf16_t* Zbuf  = (bf16_t*)(ws + o); o += (size_t)NTOK * 768 * 2;
  bf16_t* Ubuf  = (bf16_t*)(ws + o); o += (size_t)NTOK * 3072 * 2;

  // --- weight prep ---
  k_transpose_qkv<<<dim3(12, 36), 256, 0, stream>>>(wq_w, wk_w, wv_w, WqkvT);
  k_transpose_cvt<<<dim3(144), 256, 0, stream>>>(wo_w, WoT, 768, 768);
  k_transpose_cvt<<<dim3(12 * 48), 256, 0, stream>>>(w1, W1T, 768, 3072);
  k_transpose_cvt<<<dim3(48 * 12), 256, 0, stream>>>(w2, W2T, 3072, 768);
  k_concat3<<<9, 256, 0, stream>>>(wq_b, wk_b, wv_b, QKVB);

  // --- LN1 -> h ---
  k_layernorm<<<NTOK, 256, 0, stream>>>(x, ln_g, ln_b, Hbuf);

  // --- QKV projection (Q scaled, V transposed) ---
  k_gemm<128, EPI_QKV><<<dim3(18, 32), 256, 0, stream>>>(Hbuf, WqkvT, 2304, 768,
                                                         QKVB, nullptr, Qb, Kb, VbT);

  // --- attention -> o (reuses Hbuf) ---
  k_attn<<<dim3(Sn / 64, Bn * Hn), 256, 0, stream>>>(Qb, Kb, VbT, Hbuf);

  // --- y = o @ Wo + wo_b + x ---
  k_gemm<64, EPI_Y><<<dim3(6, 64), 256, 0, stream>>>(Hbuf, WoT, 768, 768,
                                                     wo_b, x, Ybuf, nullptr, nullptr);

  // --- LN2 -> z ---
  k_layernorm<<<NTOK, 256, 0, stream>>>(Ybuf, ln_g, ln_b, Zbuf);

  // --- FFN1 + exact GELU -> u ---
  k_gemm<128, EPI_GELU><<<dim3(24, 32), 256, 0, stream>>>(Zbuf, W1T, 3072, 768,
                                                          b1, nullptr, Ubuf, nullptr, nullptr);

  // --- FFN2 + b2 + y -> out ---
  k_gemm<64, EPI_OUT><<<dim3(6, 64), 256, 0, stream>>>(Ubuf, W2T, 768, 3072,
                                                       b2, Ybuf, d_out, nullptr, nullptr);
}